// Round 4
// baseline (209.795 us; speedup 1.0000x reference)
//
#include <hip/hip_runtime.h>
#include <math.h>

// Problem constants: B=2, L=2048, E=1024, H=16, D=64
constexpr int Lc = 2048, Ec = 1024, Hc = 16, Dc = 64;

typedef __attribute__((ext_vector_type(8))) short bf16x8;
typedef __attribute__((ext_vector_type(4))) float f32x4;
typedef unsigned short u16;
typedef unsigned int u32;

#define MFMA16(a, b, c) __builtin_amdgcn_mfma_f32_16x16x32_bf16(a, b, c, 0, 0, 0)

__device__ inline u16 f2bf(float f) {
  u32 u = __builtin_bit_cast(u32, f);
  u32 r = u + 0x7fff + ((u >> 16) & 1);   // RNE
  return (u16)(r >> 16);
}

__device__ inline void gld16(const void* g, void* l) {
  __builtin_amdgcn_global_load_lds(
      (const __attribute__((address_space(1))) u32*)g,
      (__attribute__((address_space(3))) u32*)l, 16, 0, 0);
}

// =====================================================================
// Prepass: fp32 -> bf16 for x (4M), w_qkv Q+V rows (2M fused), w_out (1M).
// =====================================================================
constexpr size_t XN = (size_t)4096 * 1024;
constexpr size_t WQN = (size_t)2048 * 1024;
constexpr size_t WON = (size_t)1024 * 1024;

__global__ __launch_bounds__(256) void convert_all(
    const float* __restrict__ x, const float* __restrict__ wqkv,
    const float* __restrict__ wout, u16* __restrict__ xb,
    u16* __restrict__ wqb, u16* __restrict__ wob)
{
  const size_t i = ((size_t)blockIdx.x * 256 + threadIdx.x) * 4;
  float4 v;
  u16* dst;
  if (i < XN) {
    v = *(const float4*)(x + i);
    dst = xb + i;
  } else if (i < XN + WQN) {
    const size_t off = i - XN;
    const size_t row = off >> 10, col = off & 1023;
    const size_t srow = row + ((row >> 10) << 10);   // skip K rows of w_qkv
    v = *(const float4*)(wqkv + srow * 1024 + col);
    dst = wqb + off;
  } else {
    const size_t off = i - XN - WQN;
    v = *(const float4*)(wout + off);
    dst = wob + off;
  }
  u16 o0 = f2bf(v.x), o1 = f2bf(v.y), o2 = f2bf(v.z), o3 = f2bf(v.w);
  dst[0] = o0; dst[1] = o1; dst[2] = o2; dst[3] = o3;
}

// =====================================================================
// QV GEMM (bf16 MFMA): M=4096, N=2048 (fused Q|V), K=1024.
// Q is pre-scaled by 1/8 (exact in bf16) so attention needs no scale mul.
// =====================================================================
__global__ __launch_bounds__(256) void gemm_qv(
    const u16* __restrict__ A, const u16* __restrict__ W,
    const float* __restrict__ bqkv, u16* __restrict__ Q, u16* __restrict__ V)
{
  __shared__ u16 As[128 * 32];
  __shared__ u16 Bs[128 * 32];
  const int tid = threadIdx.x;
  const int w = tid >> 6, lane = tid & 63;
  const int quad = lane >> 4, l16 = lane & 15;
  const int wm = w >> 1, wn = w & 1;
  const int rowTile = blockIdx.y * 128;
  const int colTile = blockIdx.x * 128;

  const int r0 = tid >> 2, o0 = (tid & 3) * 8;
  const u16* Ab0 = A + (size_t)(rowTile + r0) * 1024 + o0;
  const u16* Ab1 = A + (size_t)(rowTile + r0 + 64) * 1024 + o0;
  const u16* Bb0 = W + (size_t)(colTile + r0) * 1024 + o0;
  const u16* Bb1 = W + (size_t)(colTile + r0 + 64) * 1024 + o0;
  u16* lA0 = &As[(size_t)tid * 8];
  u16* lA1 = &As[(size_t)(tid + 256) * 8];
  u16* lB0 = &Bs[(size_t)tid * 8];
  u16* lB1 = &Bs[(size_t)(tid + 256) * 8];

  f32x4 acc[4][4] = {};

  for (int k0 = 0; k0 < 1024; k0 += 32) {
    __syncthreads();
    gld16(Ab0 + k0, lA0);
    gld16(Ab1 + k0, lA1);
    gld16(Bb0 + k0, lB0);
    gld16(Bb1 + k0, lB1);
    __syncthreads();
    bf16x8 af[4], bf[4];
#pragma unroll
    for (int s = 0; s < 4; ++s)
      af[s] = *(const bf16x8*)&As[(wm * 64 + s * 16 + l16) * 32 + quad * 8];
#pragma unroll
    for (int n = 0; n < 4; ++n)
      bf[n] = *(const bf16x8*)&Bs[(wn * 64 + n * 16 + l16) * 32 + quad * 8];
#pragma unroll
    for (int s = 0; s < 4; ++s)
#pragma unroll
      for (int n = 0; n < 4; ++n)
        acc[s][n] = MFMA16(af[s], bf[n], acc[s][n]);
  }

#pragma unroll
  for (int n = 0; n < 4; ++n) {
    const int gn = colTile + wn * 64 + n * 16 + l16;   // fused col 0..2047
    const bool isV = gn >= 1024;
    const float bias = bqkv[gn + (isV ? 1024 : 0)];
    const float scl = isV ? 1.0f : 0.125f;             // fold 1/sqrt(d) into Q
    const int h = (gn & 1023) >> 6, d = gn & 63;
    u16* dst = isV ? V : Q;
#pragma unroll
    for (int s = 0; s < 4; ++s) {
#pragma unroll
      for (int r = 0; r < 4; ++r) {
        const int gm = rowTile + wm * 64 + s * 16 + quad * 4 + r;
        const int b = gm >> 11, l = gm & 2047;
        dst[(((size_t)(b * Hc + h)) * Lc + l) * Dc + d] = f2bf((acc[s][n][r] + bias) * scl);
      }
    }
  }
}

// =====================================================================
// Flash attention (bug-faithful: scores = Q.V^T, Q pre-scaled by 1/8).
// Transposed pipeline: S^T = V.Q^T (MFMA A=V from GLOBAL, B=Q regs),
// exp in C-layout gives P^T whose rows pack to b64 LDS writes of
// Ps[q][key]; O^T = V^T.P^T (A=VsT swizzled LDS, B=Ps b128 reads).
// Epilogue untransposes into the bugged reshape layout.
// Block = 4 waves x 64 q-rows = 256 q-rows.  Grid (8, 32) = 256 blocks.
// =====================================================================
constexpr int VTSTR = 72;   // VsT row stride (u16); swizzle col^=(d&0x38)
constexpr int PSTR = 88;    // Ps row stride (u16)

__global__ __launch_bounds__(256, 1) void attn_mfma(
    const u16* __restrict__ Q, const u16* __restrict__ V,
    u16* __restrict__ outA)
{
  __shared__ u16 VsT[64 * VTSTR];       // [d][key^] transposed V tile
  __shared__ u16 Ps[256 * PSTR];        // [q_local][key] P rows (per-wave slices)
  const int tid = threadIdx.x;
  const int w = tid >> 6, lane = tid & 63;
  const int quad = lane >> 4, l16 = lane & 15;
  const int q0 = blockIdx.x * 256;
  const int bh = blockIdx.y;
  const int b = bh >> 4, h = bh & 15;
  const u16* Qb = Q + (size_t)bh * Lc * Dc;
  const u16* Vb = V + (size_t)bh * Lc * Dc;
  const int wq0 = q0 + w * 64;          // this wave's first q row
  const int nt = (q0 >> 6) + 4;         // 64-key tiles covering 0..q0+255

  // Q B-fragments: B[k=d][n=q] read from Q[q][d] rows (cached all tiles)
  bf16x8 qf[4][2];
#pragma unroll
  for (int s = 0; s < 4; ++s)
#pragma unroll
    for (int kk = 0; kk < 2; ++kk)
      qf[s][kk] = *(const bf16x8*)(Qb + (size_t)(wq0 + s * 16 + l16) * 64 + kk * 32 + quad * 8);

  f32x4 O[4][4] = {};                   // O^T acc: [db][s], elem r -> d=db*16+quad*4+r, q=wq0+s*16+l16
  float lsum[4] = {0.f, 0.f, 0.f, 0.f};

  const int vr0 = tid >> 3, vd0 = (tid & 7) * 8;   // staging coords
  // prologue: staging regs + S^T A-fragments for tile 0
  bf16x8 v0 = *(const bf16x8*)(Vb + (size_t)vr0 * 64 + vd0);
  bf16x8 v1 = *(const bf16x8*)(Vb + (size_t)(vr0 + 32) * 64 + vd0);
  bf16x8 av[4][2];
#pragma unroll
  for (int nb = 0; nb < 4; ++nb)
#pragma unroll
    for (int kk = 0; kk < 2; ++kk)
      av[nb][kk] = *(const bf16x8*)(Vb + (size_t)(nb * 16 + l16) * 64 + kk * 32 + quad * 8);

  for (int t = 0; t < nt; ++t) {
    const int kt = t * 64;
    __syncthreads();                    // prev compute's VsT reads done
    // stage transposed V tile (swizzled, conflict-free)
#pragma unroll
    for (int j = 0; j < 8; ++j) {
      const int d = vd0 + j, sw = d & 0x38;
      VsT[d * VTSTR + (vr0 ^ sw)] = (u16)v0[j];
      VsT[d * VTSTR + ((vr0 + 32) ^ sw)] = (u16)v1[j];
    }
    if (t + 1 < nt) {                   // prefetch next tile's staging regs
      v0 = *(const bf16x8*)(Vb + (size_t)(kt + 64 + vr0) * 64 + vd0);
      v1 = *(const bf16x8*)(Vb + (size_t)(kt + 96 + vr0) * 64 + vd0);
    }
    __syncthreads();
    if (kt > wq0) continue;             // wave-uniform skip (barriers stay uniform)

    // ---- S^T = V Q^T ; exp ; pack P rows to Ps[q][key] ----
    const bool diag = (kt == wq0);
#pragma unroll
    for (int s = 0; s < 4; ++s) {
      f32x4 sf[4] = {};
#pragma unroll
      for (int nb = 0; nb < 4; ++nb) {
        sf[nb] = MFMA16(av[nb][0], qf[s][0], sf[nb]);
        sf[nb] = MFMA16(av[nb][1], qf[s][1], sf[nb]);
      }
#pragma unroll
      for (int nb = 0; nb < 4; ++nb) {
        float p[4];
#pragma unroll
        for (int r = 0; r < 4; ++r) {
          float pv = __expf(sf[nb][r]);  // bounded: Q pre-scaled, no max needed
          if (diag && (nb * 16 + quad * 4 + r > s * 16 + l16)) pv = 0.f;
          p[r] = pv;
          lsum[s] += pv;
        }
        const u32 lo = (u32)f2bf(p[0]) | ((u32)f2bf(p[1]) << 16);
        const u32 hi = (u32)f2bf(p[2]) | ((u32)f2bf(p[3]) << 16);
        *(uint2*)&Ps[(size_t)(w * 64 + s * 16 + l16) * PSTR + nb * 16 + quad * 4] =
            make_uint2(lo, hi);
      }
    }
    // prefetch next tile's A-fragments (if this wave computes it)
    if (kt + 64 <= wq0) {
#pragma unroll
      for (int nb = 0; nb < 4; ++nb)
#pragma unroll
        for (int kk = 0; kk < 2; ++kk)
          av[nb][kk] = *(const bf16x8*)(Vb + (size_t)(kt + 64 + nb * 16 + l16) * 64 + kk * 32 + quad * 8);
    }
    __asm__ volatile("s_waitcnt lgkmcnt(0)");   // Ps writes visible in-wave

    // ---- O^T += V^T P^T ----
    bf16x8 vt[4][2], pb[4][2];
#pragma unroll
    for (int db = 0; db < 4; ++db) {
      const int d = db * 16 + l16, sw = d & 0x38;
      vt[db][0] = *(const bf16x8*)&VsT[d * VTSTR + ((quad * 8) ^ sw)];
      vt[db][1] = *(const bf16x8*)&VsT[d * VTSTR + ((32 + quad * 8) ^ sw)];
    }
#pragma unroll
    for (int s = 0; s < 4; ++s) {
      pb[s][0] = *(const bf16x8*)&Ps[(size_t)(w * 64 + s * 16 + l16) * PSTR + quad * 8];
      pb[s][1] = *(const bf16x8*)&Ps[(size_t)(w * 64 + s * 16 + l16) * PSTR + 32 + quad * 8];
    }
#pragma unroll
    for (int db = 0; db < 4; ++db)
#pragma unroll
      for (int s = 0; s < 4; ++s) {
        O[db][s] = MFMA16(vt[db][0], pb[s][0], O[db][s]);
        O[db][s] = MFMA16(vt[db][1], pb[s][1], O[db][s]);
      }
  }

  // epilogue: reduce row sums across quads, untranspose, store bugged layout
#pragma unroll
  for (int s = 0; s < 4; ++s) {
    float l = lsum[s];
    l += __shfl_xor(l, 16);
    l += __shfl_xor(l, 32);
    const float inv = 1.f / l;                       // row sum for q = wq0+s*16+l16
    const int row = h * 128 + (wq0 >> 4) + s;        // (q>>4) uniform in l16
    const size_t base = ((size_t)b * Lc + row) * Ec;
#pragma unroll
    for (int db = 0; db < 4; ++db) {
      const u32 lo = (u32)f2bf(O[db][s][0] * inv) | ((u32)f2bf(O[db][s][1] * inv) << 16);
      const u32 hi = (u32)f2bf(O[db][s][2] * inv) | ((u32)f2bf(O[db][s][3] * inv) << 16);
      *(uint2*)(outA + base + l16 * 64 + db * 16 + quad * 4) = make_uint2(lo, hi);
    }
  }
}

// =====================================================================
// Out GEMM: out[m][n] = sum_k Aw[m][k]*wob[n][k] + b_out[n], fp32 out.
// Tile 64(M) x 128(N), BK=32 -> grid (8, 64) = 512 blocks (2/CU).
// Wave: 32 rows x 64 cols (acc 2x4).
// =====================================================================
__global__ __launch_bounds__(256) void gemm_out(
    const u16* __restrict__ A, const u16* __restrict__ W,
    const float* __restrict__ bias, float* __restrict__ out)
{
  __shared__ u16 As[64 * 32];
  __shared__ u16 Bs[128 * 32];
  const int tid = threadIdx.x;
  const int w = tid >> 6, lane = tid & 63;
  const int quad = lane >> 4, l16 = lane & 15;
  const int wm = w & 1, wn = w >> 1;
  const int rowTile = blockIdx.y * 64;
  const int colTile = blockIdx.x * 128;

  const int r0 = tid >> 2, o0 = (tid & 3) * 8;
  const u16* Ab0 = A + (size_t)(rowTile + r0) * 1024 + o0;
  const u16* Bb0 = W + (size_t)(colTile + r0) * 1024 + o0;
  const u16* Bb1 = W + (size_t)(colTile + r0 + 64) * 1024 + o0;
  u16* lA0 = &As[(size_t)tid * 8];
  u16* lB0 = &Bs[(size_t)tid * 8];
  u16* lB1 = &Bs[(size_t)(tid + 256) * 8];

  f32x4 acc[2][4] = {};

  for (int k0 = 0; k0 < 1024; k0 += 32) {
    __syncthreads();
    gld16(Ab0 + k0, lA0);
    gld16(Bb0 + k0, lB0);
    gld16(Bb1 + k0, lB1);
    __syncthreads();
    bf16x8 af[2], bf[4];
#pragma unroll
    for (int s = 0; s < 2; ++s)
      af[s] = *(const bf16x8*)&As[(wm * 32 + s * 16 + l16) * 32 + quad * 8];
#pragma unroll
    for (int n = 0; n < 4; ++n)
      bf[n] = *(const bf16x8*)&Bs[(wn * 64 + n * 16 + l16) * 32 + quad * 8];
#pragma unroll
    for (int s = 0; s < 2; ++s)
#pragma unroll
      for (int n = 0; n < 4; ++n)
        acc[s][n] = MFMA16(af[s], bf[n], acc[s][n]);
  }

#pragma unroll
  for (int n = 0; n < 4; ++n) {
    const int gn = colTile + wn * 64 + n * 16 + l16;
    const float bn = bias[gn];
#pragma unroll
    for (int s = 0; s < 2; ++s)
#pragma unroll
      for (int r = 0; r < 4; ++r) {
        const int gm = rowTile + wm * 32 + s * 16 + quad * 4 + r;
        out[(size_t)gm * 1024 + gn] = acc[s][n][r] + bn;
      }
  }
}

// =====================================================================
extern "C" void kernel_launch(void* const* d_in, const int* in_sizes, int n_in,
                              void* d_out, int out_size, void* d_ws, size_t ws_size,
                              hipStream_t stream) {
  (void)in_sizes; (void)n_in; (void)out_size; (void)ws_size;
  const float* x     = (const float*)d_in[0];
  const float* w_qkv = (const float*)d_in[1];
  const float* b_qkv = (const float*)d_in[2];
  const float* w_out = (const float*)d_in[3];
  const float* b_out = (const float*)d_in[4];
  float* out = (float*)d_out;

  u16* xb  = (u16*)d_ws;
  u16* wqb = xb + XN;
  u16* wob = wqb + WQN;
  u16* Qw  = wob + WON;
  u16* Vw  = Qw + (size_t)2 * Hc * Lc * Dc;
  u16* Aw  = Vw + (size_t)2 * Hc * Lc * Dc;

  convert_all<<<7168, 256, 0, stream>>>(x, w_qkv, w_out, xb, wqb, wob);
  gemm_qv<<<dim3(16, 32), 256, 0, stream>>>(xb, wqb, b_qkv, Qw, Vw);
  attn_mfma<<<dim3(8, 32), 256, 0, stream>>>(Qw, Vw, Aw);
  gemm_out<<<dim3(8, 64), 256, 0, stream>>>(Aw, wob, b_out, out);
}

// Round 5
// 209.263 us; speedup vs baseline: 1.0025x; 1.0025x over previous
//
#include <hip/hip_runtime.h>
#include <math.h>

// Problem constants: B=2, L=2048, E=1024, H=16, D=64
constexpr int Lc = 2048, Ec = 1024, Hc = 16, Dc = 64;

typedef __attribute__((ext_vector_type(8))) short bf16x8;
typedef __attribute__((ext_vector_type(4))) short bf16x4;
typedef __attribute__((ext_vector_type(4))) float f32x4;
typedef unsigned short u16;
typedef unsigned int u32;

#define MFMA32(a, b, c) __builtin_amdgcn_mfma_f32_16x16x32_bf16(a, b, c, 0, 0, 0)

__device__ inline f32x4 mfma_k16(bf16x4 a, bf16x4 b, f32x4 c) {
#if __has_builtin(__builtin_amdgcn_mfma_f32_16x16x16bf16_1k)
  return __builtin_amdgcn_mfma_f32_16x16x16bf16_1k(a, b, c, 0, 0, 0);
#else
  asm("v_mfma_f32_16x16x16_bf16 %0, %1, %2, %0" : "+v"(c) : "v"(a), "v"(b));
  return c;
#endif
}

__device__ inline u16 f2bf(float f) {
  u32 u = __builtin_bit_cast(u32, f);
  u32 r = u + 0x7fff + ((u >> 16) & 1);   // RNE
  return (u16)(r >> 16);
}

__device__ inline void gld16(const void* g, void* l) {
  __builtin_amdgcn_global_load_lds(
      (const __attribute__((address_space(1))) u32*)g,
      (__attribute__((address_space(3))) u32*)l, 16, 0, 0);
}

// =====================================================================
// Prepass: fp32 -> bf16 for x (4M), w_qkv Q+V rows (2M fused), w_out (1M).
// =====================================================================
constexpr size_t XN = (size_t)4096 * 1024;
constexpr size_t WQN = (size_t)2048 * 1024;
constexpr size_t WON = (size_t)1024 * 1024;

__global__ __launch_bounds__(256) void convert_all(
    const float* __restrict__ x, const float* __restrict__ wqkv,
    const float* __restrict__ wout, u16* __restrict__ xb,
    u16* __restrict__ wqb, u16* __restrict__ wob)
{
  const size_t i = ((size_t)blockIdx.x * 256 + threadIdx.x) * 4;
  float4 v;
  u16* dst;
  if (i < XN) {
    v = *(const float4*)(x + i);
    dst = xb + i;
  } else if (i < XN + WQN) {
    const size_t off = i - XN;
    const size_t row = off >> 10, col = off & 1023;
    const size_t srow = row + ((row >> 10) << 10);   // skip K rows of w_qkv
    v = *(const float4*)(wqkv + srow * 1024 + col);
    dst = wqb + off;
  } else {
    const size_t off = i - XN - WQN;
    v = *(const float4*)(wout + off);
    dst = wob + off;
  }
  u16 o0 = f2bf(v.x), o1 = f2bf(v.y), o2 = f2bf(v.z), o3 = f2bf(v.w);
  dst[0] = o0; dst[1] = o1; dst[2] = o2; dst[3] = o3;
}

// =====================================================================
// QV GEMM (bf16 MFMA): M=4096, N=2048 (fused Q|V), K=1024.
// Q pre-scaled by 1/8.  V additionally written TRANSPOSED per head:
// VT[bh][d][l] for the attention kernel's LDS staging.
// =====================================================================
__global__ __launch_bounds__(256) void gemm_qv(
    const u16* __restrict__ A, const u16* __restrict__ W,
    const float* __restrict__ bqkv, u16* __restrict__ Q, u16* __restrict__ V,
    u16* __restrict__ VT)
{
  __shared__ u16 As[128 * 32];
  __shared__ u16 Bs[128 * 32];
  const int tid = threadIdx.x;
  const int w = tid >> 6, lane = tid & 63;
  const int quad = lane >> 4, l16 = lane & 15;
  const int wm = w >> 1, wn = w & 1;
  const int rowTile = blockIdx.y * 128;
  const int colTile = blockIdx.x * 128;

  const int r0 = tid >> 2, o0 = (tid & 3) * 8;
  const u16* Ab0 = A + (size_t)(rowTile + r0) * 1024 + o0;
  const u16* Ab1 = A + (size_t)(rowTile + r0 + 64) * 1024 + o0;
  const u16* Bb0 = W + (size_t)(colTile + r0) * 1024 + o0;
  const u16* Bb1 = W + (size_t)(colTile + r0 + 64) * 1024 + o0;
  u16* lA0 = &As[(size_t)tid * 8];
  u16* lA1 = &As[(size_t)(tid + 256) * 8];
  u16* lB0 = &Bs[(size_t)tid * 8];
  u16* lB1 = &Bs[(size_t)(tid + 256) * 8];

  f32x4 acc[4][4] = {};

  for (int k0 = 0; k0 < 1024; k0 += 32) {
    __syncthreads();
    gld16(Ab0 + k0, lA0);
    gld16(Ab1 + k0, lA1);
    gld16(Bb0 + k0, lB0);
    gld16(Bb1 + k0, lB1);
    __syncthreads();
    bf16x8 af[4], bf[4];
#pragma unroll
    for (int s = 0; s < 4; ++s)
      af[s] = *(const bf16x8*)&As[(wm * 64 + s * 16 + l16) * 32 + quad * 8];
#pragma unroll
    for (int n = 0; n < 4; ++n)
      bf[n] = *(const bf16x8*)&Bs[(wn * 64 + n * 16 + l16) * 32 + quad * 8];
#pragma unroll
    for (int s = 0; s < 4; ++s)
#pragma unroll
      for (int n = 0; n < 4; ++n)
        acc[s][n] = MFMA32(af[s], bf[n], acc[s][n]);
  }

  const bool isV = (colTile >= 1024);      // uniform per block
#pragma unroll
  for (int n = 0; n < 4; ++n) {
    const int gn = colTile + wn * 64 + n * 16 + l16;   // fused col 0..2047
    const float bias = bqkv[gn + (isV ? 1024 : 0)];
    const float scl = isV ? 1.0f : 0.125f;             // fold 1/sqrt(d) into Q
    const int h = (gn & 1023) >> 6, d = gn & 63;
    u16* dst = isV ? V : Q;
#pragma unroll
    for (int s = 0; s < 4; ++s) {
#pragma unroll
      for (int r = 0; r < 4; ++r) {
        const int gm = rowTile + wm * 64 + s * 16 + quad * 4 + r;
        const int b = gm >> 11, l = gm & 2047;
        const u16 val = f2bf((acc[s][n][r] + bias) * scl);
        const size_t bhh = (size_t)(b * Hc + h);
        dst[(bhh * Lc + l) * Dc + d] = val;
        if (isV) VT[(bhh * Dc + d) * Lc + l] = val;
      }
    }
  }
}

// =====================================================================
// Flash attention (bug-faithful: scores = Q.V^T, Q pre-scaled by 1/8).
// Transposed pipeline with ZERO P round-trip:
//   S^T = V.Q^T     (16x16x32 MFMA; A=V rows from global, B=Q regs)
//   P^T = exp(S^T)  in C-layout registers (no running max needed)
//   O^T = V^T.P^T   (16x16x16 MFMA; B=P^T DIRECT from C-layout regs,
//                    A=V^T b64 reads from VsT staged off global VT)
// Wave = 32 q-rows, block = 4 waves = 128 q-rows.  Grid (16,32)=512,
// 2 blocks/CU, heavy-first (qt = 15-bx) for LPT balance.
// =====================================================================
constexpr int VTSTR = 68;   // VsT row stride (u16)

__global__ __launch_bounds__(256, 2) void attn_mfma(
    const u16* __restrict__ Q, const u16* __restrict__ V,
    const u16* __restrict__ VT, u16* __restrict__ outA)
{
  __shared__ u16 VsT[64 * VTSTR];          // [d][key] for current 64-key tile
  const int tid = threadIdx.x;
  const int w = tid >> 6, lane = tid & 63;
  const int quad = lane >> 4, l16 = lane & 15;
  const int qt = 15 - (int)blockIdx.x;     // heavy-first
  const int q0 = qt * 128;
  const int bh = blockIdx.y;
  const int b = bh >> 4, h = bh & 15;
  const u16* Qb = Q + (size_t)bh * Lc * Dc;
  const u16* Vb = V + (size_t)bh * Lc * Dc;
  const u16* VTb = VT + (size_t)bh * Dc * Lc;
  const int wq0 = q0 + w * 32;             // this wave's first q row
  const int nt = 2 * qt + 2;               // 64-key tiles covering 0..q0+127

  // Q B-fragments (persist across all tiles): q = wq0+s*16+l16, k=d
  bf16x8 qf[2][2];
#pragma unroll
  for (int s = 0; s < 2; ++s)
#pragma unroll
    for (int kk = 0; kk < 2; ++kk)
      qf[s][kk] = *(const bf16x8*)(Qb + (size_t)(wq0 + s * 16 + l16) * 64 + kk * 32 + quad * 8);

  f32x4 O[4][2] = {};                      // O^T acc [db][s]: d=db*16+quad*4+r, q=wq0+s*16+l16
  float lsum[2] = {0.f, 0.f};

  // staging coords: d = sd, keys sk..sk+15 (two b128)
  const int sd = tid >> 2, sk = (tid & 3) * 16;
  bf16x8 stg0 = *(const bf16x8*)(VTb + (size_t)sd * Lc + sk);
  bf16x8 stg1 = *(const bf16x8*)(VTb + (size_t)sd * Lc + sk + 8);
  // S^T A-fragments for tile 0: key = nb*16+l16, k=d
  bf16x8 av[4][2];
#pragma unroll
  for (int nb = 0; nb < 4; ++nb)
#pragma unroll
    for (int kk = 0; kk < 2; ++kk)
      av[nb][kk] = *(const bf16x8*)(Vb + (size_t)(nb * 16 + l16) * 64 + kk * 32 + quad * 8);

  for (int t = 0; t < nt; ++t) {
    const int kt = t * 64;
    __syncthreads();                       // prev compute's VsT reads done
    *(bf16x8*)&VsT[sd * VTSTR + sk] = stg0;
    *(bf16x8*)&VsT[sd * VTSTR + sk + 8] = stg1;
    if (t + 1 < nt) {                      // prefetch next tile (flight over compute)
      stg0 = *(const bf16x8*)(VTb + (size_t)sd * Lc + kt + 64 + sk);
      stg1 = *(const bf16x8*)(VTb + (size_t)sd * Lc + kt + 64 + sk + 8);
    }
    __syncthreads();
    if (kt > wq0 + 31) continue;           // wave-uniform skip; barriers stay uniform

    // ---- S^T = V Q^T ----
    f32x4 sf[2][4] = {};
#pragma unroll
    for (int s = 0; s < 2; ++s)
#pragma unroll
      for (int nb = 0; nb < 4; ++nb) {
        sf[s][nb] = MFMA32(av[nb][0], qf[s][0], sf[s][nb]);
        sf[s][nb] = MFMA32(av[nb][1], qf[s][1], sf[s][nb]);
      }
    if (kt + 64 <= wq0 + 31) {             // prefetch next tile's A-frags
#pragma unroll
      for (int nb = 0; nb < 4; ++nb)
#pragma unroll
        for (int kk = 0; kk < 2; ++kk)
          av[nb][kk] = *(const bf16x8*)(Vb + (size_t)(kt + 64 + nb * 16 + l16) * 64 + kk * 32 + quad * 8);
    }

    // V^T A-frags for PV: d = db*16+l16, key = nb*16+quad*4+j  (b64 reads)
    bf16x4 vt[4][4];                       // [nb][db]
#pragma unroll
    for (int nb = 0; nb < 4; ++nb)
#pragma unroll
      for (int db = 0; db < 4; ++db)
        vt[nb][db] = *(const bf16x4*)&VsT[(db * 16 + l16) * VTSTR + nb * 16 + quad * 4];

    // ---- exp -> P^T (registers, already in B-layout for K16 MFMA) -> O^T ----
    const bool needmask = (kt + 63 > wq0);
#pragma unroll
    for (int s = 0; s < 2; ++s) {
      bf16x4 pp[4];
#pragma unroll
      for (int nb = 0; nb < 4; ++nb) {
        float p[4];
#pragma unroll
        for (int r = 0; r < 4; ++r) {
          float pv = __expf(sf[s][nb][r]); // bounded: Q pre-scaled, no max needed
          if (needmask && (kt + nb * 16 + quad * 4 + r > wq0 + s * 16 + l16)) pv = 0.f;
          p[r] = pv;
          lsum[s] += pv;
        }
        pp[nb] = (bf16x4){(short)f2bf(p[0]), (short)f2bf(p[1]),
                          (short)f2bf(p[2]), (short)f2bf(p[3])};
      }
#pragma unroll
      for (int nb = 0; nb < 4; ++nb)
#pragma unroll
        for (int db = 0; db < 4; ++db)
          O[db][s] = mfma_k16(vt[nb][db], pp[nb], O[db][s]);
    }
  }

  // epilogue: reduce row sums across quads, untranspose, bugged-reshape store
#pragma unroll
  for (int s = 0; s < 2; ++s) {
    float l = lsum[s];
    l += __shfl_xor(l, 16);
    l += __shfl_xor(l, 32);
    const float inv = 1.f / l;             // row sum for q = wq0+s*16+l16
    const int q = wq0 + s * 16 + l16;
    const int row = h * 128 + (q >> 4);
    const size_t base = ((size_t)b * Lc + row) * Ec + ((q & 15) << 6);
#pragma unroll
    for (int db = 0; db < 4; ++db) {
      const u32 lo = (u32)f2bf(O[db][s][0] * inv) | ((u32)f2bf(O[db][s][1] * inv) << 16);
      const u32 hi = (u32)f2bf(O[db][s][2] * inv) | ((u32)f2bf(O[db][s][3] * inv) << 16);
      *(uint2*)(outA + base + db * 16 + quad * 4) = make_uint2(lo, hi);
    }
  }
}

// =====================================================================
// Out GEMM: out[m][n] = sum_k Aw[m][k]*wob[n][k] + b_out[n], fp32 out.
// Tile 64(M) x 128(N), BK=32 -> grid (8, 64) = 512 blocks (2/CU).
// =====================================================================
__global__ __launch_bounds__(256) void gemm_out(
    const u16* __restrict__ A, const u16* __restrict__ W,
    const float* __restrict__ bias, float* __restrict__ out)
{
  __shared__ u16 As[64 * 32];
  __shared__ u16 Bs[128 * 32];
  const int tid = threadIdx.x;
  const int w = tid >> 6, lane = tid & 63;
  const int quad = lane >> 4, l16 = lane & 15;
  const int wm = w & 1, wn = w >> 1;
  const int rowTile = blockIdx.y * 64;
  const int colTile = blockIdx.x * 128;

  const int r0 = tid >> 2, o0 = (tid & 3) * 8;
  const u16* Ab0 = A + (size_t)(rowTile + r0) * 1024 + o0;
  const u16* Bb0 = W + (size_t)(colTile + r0) * 1024 + o0;
  const u16* Bb1 = W + (size_t)(colTile + r0 + 64) * 1024 + o0;
  u16* lA0 = &As[(size_t)tid * 8];
  u16* lB0 = &Bs[(size_t)tid * 8];
  u16* lB1 = &Bs[(size_t)(tid + 256) * 8];

  f32x4 acc[2][4] = {};

  for (int k0 = 0; k0 < 1024; k0 += 32) {
    __syncthreads();
    gld16(Ab0 + k0, lA0);
    gld16(Bb0 + k0, lB0);
    gld16(Bb1 + k0, lB1);
    __syncthreads();
    bf16x8 af[2], bf[4];
#pragma unroll
    for (int s = 0; s < 2; ++s)
      af[s] = *(const bf16x8*)&As[(wm * 32 + s * 16 + l16) * 32 + quad * 8];
#pragma unroll
    for (int n = 0; n < 4; ++n)
      bf[n] = *(const bf16x8*)&Bs[(wn * 64 + n * 16 + l16) * 32 + quad * 8];
#pragma unroll
    for (int s = 0; s < 2; ++s)
#pragma unroll
      for (int n = 0; n < 4; ++n)
        acc[s][n] = MFMA32(af[s], bf[n], acc[s][n]);
  }

#pragma unroll
  for (int n = 0; n < 4; ++n) {
    const int gn = colTile + wn * 64 + n * 16 + l16;
    const float bn = bias[gn];
#pragma unroll
    for (int s = 0; s < 2; ++s)
#pragma unroll
      for (int r = 0; r < 4; ++r) {
        const int gm = rowTile + wm * 32 + s * 16 + quad * 4 + r;
        out[(size_t)gm * 1024 + gn] = acc[s][n][r] + bn;
      }
  }
}

// =====================================================================
extern "C" void kernel_launch(void* const* d_in, const int* in_sizes, int n_in,
                              void* d_out, int out_size, void* d_ws, size_t ws_size,
                              hipStream_t stream) {
  (void)in_sizes; (void)n_in; (void)out_size; (void)ws_size;
  const float* x     = (const float*)d_in[0];
  const float* w_qkv = (const float*)d_in[1];
  const float* b_qkv = (const float*)d_in[2];
  const float* w_out = (const float*)d_in[3];
  const float* b_out = (const float*)d_in[4];
  float* out = (float*)d_out;

  constexpr size_t QVN = (size_t)2 * Hc * Lc * Dc;   // 4M elements
  u16* xb  = (u16*)d_ws;
  u16* wqb = xb + XN;
  u16* wob = wqb + WQN;
  u16* Qw  = wob + WON;
  u16* Vw  = Qw + QVN;
  u16* VTw = Vw + QVN;
  u16* Aw  = VTw + QVN;

  convert_all<<<7168, 256, 0, stream>>>(x, w_qkv, w_out, xb, wqb, wob);
  gemm_qv<<<dim3(16, 32), 256, 0, stream>>>(xb, wqb, b_qkv, Qw, Vw, VTw);
  attn_mfma<<<dim3(16, 32), 256, 0, stream>>>(Qw, Vw, VTw, Aw);
  gemm_out<<<dim3(8, 64), 256, 0, stream>>>(Aw, wob, b_out, out);
}